// Round 1
// baseline (284.246 us; speedup 1.0000x reference)
//
#include <hip/hip_runtime.h>

// Problem constants
#define NB 32
#define NS 2048
#define ND 512
#define NFF 512
#define SCALE 0.044194173824159216f

// Streaming decomposition: 64 chunks per batch, 32 rows per chunk
#define CPB 64
#define ROWS 32

__device__ __forceinline__ float dot4(float4 a, float4 b) {
    return a.x * b.x + a.y * b.y + a.z * b.z + a.w * b.w;
}

__device__ __forceinline__ float wave_reduce(float p) {
#pragma unroll
    for (int m = 1; m < 64; m <<= 1) p += __shfl_xor(p, m, 64);
    return p;
}

// ---- K1: xwp[blk][d] = sum_{s in chunk} Wt[s]*x[b,s,d]  (pass 1) -----------
// grid = NB*64 = 2048 blocks, 256 threads. Blocks 0..31 also zero xt/st for
// batch bz=blockIdx (k_ta_xt runs strictly after in stream order).
__global__ void __launch_bounds__(256) k_xw(const float* __restrict__ x,
                                            const float* __restrict__ Wt,
                                            float* __restrict__ xwp,
                                            float* __restrict__ xt,
                                            float* __restrict__ st) {
    const int b = blockIdx.x >> 6;
    const int chunk = blockIdx.x & 63;
    const int s0 = chunk * ROWS;
    const int t = threadIdx.x;
    const int col = t & 127;   // float4 column
    const int half = t >> 7;   // row interleave (0/1)

    if (blockIdx.x < NB) {     // zero atomic accumulators for batch bz
        const int bz = blockIdx.x;
        xt[bz * ND + t] = 0.f;
        xt[bz * ND + 256 + t] = 0.f;
        if (t == 0) st[bz] = 0.f;
    }

    const float4* xb = (const float4*)(x + (size_t)b * NS * ND);
    float4 acc = make_float4(0.f, 0.f, 0.f, 0.f);
#pragma unroll 4
    for (int i = 0; i < 16; i++) {
        int s = s0 + half + 2 * i;
        float w = Wt[s];
        float4 v = xb[(size_t)s * 128 + col];
        acc.x += w * v.x; acc.y += w * v.y; acc.z += w * v.z; acc.w += w * v.w;
    }
    __shared__ float4 red[128];
    if (half == 1) red[col] = acc;
    __syncthreads();
    if (half == 0) {
        float4 o = red[col];
        o.x += acc.x; o.y += acc.y; o.z += acc.z; o.w += acc.w;
        ((float4*)xwp)[(size_t)blockIdx.x * 128 + col] = o;
    }
}

// ---- K2: xw[b][d] = sum_c xwp[b,c][d]; block 0 also computes sw=sum(Wt) ----
// grid = 64 blocks (b x 2 d-halves), 256 threads. Reads xwp exactly once.
__global__ void __launch_bounds__(256) k_xwred(const float* __restrict__ xwp,
                                               const float* __restrict__ Wt,
                                               float* __restrict__ xw,
                                               float* __restrict__ sw) {
    const int b = blockIdx.x >> 1;
    const int d0 = (blockIdx.x & 1) * 256;
    const int t = threadIdx.x;
    const float* p = xwp + (size_t)b * CPB * ND + d0 + t;
    float a = 0.f;
#pragma unroll 8
    for (int c = 0; c < CPB; c++) a += p[(size_t)c * ND];
    xw[b * ND + d0 + t] = a;
    if (blockIdx.x == 0 && t < 64) {
        float s = 0.f;
#pragma unroll
        for (int i = 0; i < 32; i++) s += Wt[t + 64 * i];
        s = wave_reduce(s);
        if (t == 0) sw[0] = s;
    }
}

// ---- K3: kwS[b,f] = SCALE*(Wk[f,:].xw[b,:] + bk[f]*sw) ---------------------
// grid = 512 blocks (32 b x 16 groups of 32 f), 256 threads, 8 f per wave.
__global__ void __launch_bounds__(256) k_kw(const float* __restrict__ xw,
                                            const float* __restrict__ Wk,
                                            const float* __restrict__ bk,
                                            const float* __restrict__ sw,
                                            float* __restrict__ kwS) {
    const int b = blockIdx.x >> 4;
    const int f0 = (blockIdx.x & 15) * 32;
    const int t = threadIdx.x;
    const int wv = t >> 6;
    const int lane = t & 63;
    const float4* xw4 = (const float4*)(xw + b * ND);
    const float4 xa = xw4[lane];
    const float4 xc = xw4[64 + lane];
    const float sws = sw[0];
#pragma unroll
    for (int j = 0; j < 8; j++) {
        int f = f0 + wv * 8 + j;
        const float4* wr = (const float4*)(Wk + (size_t)f * ND);
        float pd = dot4(xa, wr[lane]) + dot4(xc, wr[64 + lane]);
        pd = wave_reduce(pd);
        if (lane == 0) kwS[b * NFF + f] = SCALE * (pd + bk[f] * sws);
    }
}

// ---- K4: wqs[b,d] = sum_f kwS[b,f]*Wq[f,d]; cb2[b] = kwS.bq + bt -----------
// grid = 64 blocks (32 b x 2 d-halves), 256 threads. Full sum, no atomics,
// coalesced 1KB row segments of Wq.
__global__ void __launch_bounds__(256) k_wqs(const float* __restrict__ kwS,
                                             const float* __restrict__ Wq,
                                             const float* __restrict__ bq,
                                             const float* __restrict__ bt,
                                             float* __restrict__ wqs,
                                             float* __restrict__ cb2) {
    const int b = blockIdx.x >> 1;
    const int d0 = (blockIdx.x & 1) * 256;
    const int t = threadIdx.x;
    __shared__ float sk[NFF];
    __shared__ float red[256];
    sk[t] = kwS[b * NFF + t];
    sk[256 + t] = kwS[b * NFF + 256 + t];
    __syncthreads();
    const float* wp = Wq + d0 + t;
    float a0 = 0.f, a1 = 0.f, a2 = 0.f, a3 = 0.f;
#pragma unroll 4
    for (int f = 0; f < NFF; f += 4) {
        a0 += sk[f]     * wp[(size_t)f * ND];
        a1 += sk[f + 1] * wp[(size_t)(f + 1) * ND];
        a2 += sk[f + 2] * wp[(size_t)(f + 2) * ND];
        a3 += sk[f + 3] * wp[(size_t)(f + 3) * ND];
    }
    wqs[b * ND + d0 + t] = (a0 + a1) + (a2 + a3);
    if ((blockIdx.x & 1) == 0) {
        float v = sk[t] * bq[t] + sk[256 + t] * bq[256 + t];
        red[t] = v;
        __syncthreads();
        for (int off = 128; off > 0; off >>= 1) {
            if (t < off) red[t] += red[t + off];
            __syncthreads();
        }
        if (t == 0) cb2[b] = red[0] + bt[0];
    }
}

// ---- K5: ta = x.wqs + cb2; xt[b,d] += sum_s ta*x (atomic); st[b] += sum ta -
// grid = 2048 blocks (32 rows), 256 threads = 4 waves, 8 rows/wave.
// 8-way ILP across the per-row shuffle reduction trees.
__global__ void __launch_bounds__(256) k_ta_xt(const float* __restrict__ x,
                                               const float* __restrict__ wqs,
                                               const float* __restrict__ cb2,
                                               float* __restrict__ xt,
                                               float* __restrict__ st) {
    const int b = blockIdx.x >> 6;
    const int chunk = blockIdx.x & 63;
    const int wv = threadIdx.x >> 6;
    const int lane = threadIdx.x & 63;
    const float4* xb = (const float4*)(x + (size_t)b * NS * ND);
    const float4* wq4 = (const float4*)(wqs + b * ND);
    const float4 w0 = wq4[lane];
    const float4 w1 = wq4[64 + lane];
    const float c = cb2[b];

    float4 v0[8], v1[8];
    float pd[8];
#pragma unroll
    for (int i = 0; i < 8; i++) {
        int s = chunk * ROWS + wv * 8 + i;
        v0[i] = xb[(size_t)s * 128 + lane];
        v1[i] = xb[(size_t)s * 128 + 64 + lane];
        pd[i] = dot4(v0[i], w0) + dot4(v1[i], w1);
    }
#pragma unroll
    for (int m = 1; m < 64; m <<= 1) {
#pragma unroll
        for (int i = 0; i < 8; i++) pd[i] += __shfl_xor(pd[i], m, 64);
    }
    float4 a0 = make_float4(0.f, 0.f, 0.f, 0.f);
    float4 a1 = make_float4(0.f, 0.f, 0.f, 0.f);
    float sta = 0.f;
#pragma unroll
    for (int i = 0; i < 8; i++) {
        float ta = pd[i] + c;
        a0.x += ta * v0[i].x; a0.y += ta * v0[i].y; a0.z += ta * v0[i].z; a0.w += ta * v0[i].w;
        a1.x += ta * v1[i].x; a1.y += ta * v1[i].y; a1.z += ta * v1[i].z; a1.w += ta * v1[i].w;
        sta += ta;
    }
    __shared__ float4 sh0[4][64];
    __shared__ float4 sh1[4][64];
    __shared__ float sW[4];
    sh0[wv][lane] = a0;
    sh1[wv][lane] = a1;
    if (lane == 0) sW[wv] = sta;
    __syncthreads();
    const int t = threadIdx.x;
    float* xbt = xt + b * ND;
    if (t < 64) {
        float4 s0 = sh0[0][t], s1 = sh0[1][t], s2 = sh0[2][t], s3 = sh0[3][t];
        atomicAdd(&xbt[4 * t + 0], s0.x + s1.x + s2.x + s3.x);
        atomicAdd(&xbt[4 * t + 1], s0.y + s1.y + s2.y + s3.y);
        atomicAdd(&xbt[4 * t + 2], s0.z + s1.z + s2.z + s3.z);
        atomicAdd(&xbt[4 * t + 3], s0.w + s1.w + s2.w + s3.w);
    } else if (t < 128) {
        int l = t - 64;
        float4 s0 = sh1[0][l], s1 = sh1[1][l], s2 = sh1[2][l], s3 = sh1[3][l];
        atomicAdd(&xbt[256 + 4 * l + 0], s0.x + s1.x + s2.x + s3.x);
        atomicAdd(&xbt[256 + 4 * l + 1], s0.y + s1.y + s2.y + s3.y);
        atomicAdd(&xbt[256 + 4 * l + 2], s0.z + s1.z + s2.z + s3.z);
        atomicAdd(&xbt[256 + 4 * l + 3], s0.w + s1.w + s2.w + s3.w);
    } else if (t == 128) {
        atomicAdd(&st[b], sW[0] + sW[1] + sW[2] + sW[3]);
    }
}

// ---- K6: out[b,f] = Wv[f,:].xt[b,:] + bv[f]*st[b] --------------------------
// grid = 512 blocks (32 b x 16 groups of 32 f), 256 threads, 8 f per wave.
__global__ void __launch_bounds__(256) k_out(const float* __restrict__ xt,
                                             const float* __restrict__ st,
                                             const float* __restrict__ Wv,
                                             const float* __restrict__ bv,
                                             float* __restrict__ out) {
    const int b = blockIdx.x >> 4;
    const int f0 = (blockIdx.x & 15) * 32;
    const int t = threadIdx.x;
    const int wv = t >> 6;
    const int lane = t & 63;
    const float4* xt4 = (const float4*)(xt + b * ND);
    const float4 xa = xt4[lane];
    const float4 xc = xt4[64 + lane];
    const float stb = st[b];
#pragma unroll
    for (int j = 0; j < 8; j++) {
        int f = f0 + wv * 8 + j;
        const float4* wr = (const float4*)(Wv + (size_t)f * ND);
        float pd = dot4(xa, wr[lane]) + dot4(xc, wr[64 + lane]);
        pd = wave_reduce(pd);
        if (lane == 0) out[b * NFF + f] = pd + bv[f] * stb;
    }
}

extern "C" void kernel_launch(void* const* d_in, const int* in_sizes, int n_in,
                              void* d_out, int out_size, void* d_ws, size_t ws_size,
                              hipStream_t stream) {
    const float* x  = (const float*)d_in[0];
    const float* Wq = (const float*)d_in[1];
    const float* bq = (const float*)d_in[2];
    const float* Wk = (const float*)d_in[3];
    const float* bk = (const float*)d_in[4];
    const float* Wv = (const float*)d_in[5];
    const float* bv = (const float*)d_in[6];
    const float* Wt = (const float*)d_in[7];
    const float* bt = (const float*)d_in[8];
    float* out = (float*)d_out;

    float* w = (float*)d_ws;
    float* xwp = w;                  // 2048*512 = 1048576 floats
    float* xw  = w + 1048576;        // 32*512 = 16384
    float* kwS = w + 1064960;        // 16384
    float* wqs = w + 1081344;        // 16384
    float* cb2 = w + 1097728;        // 32
    float* xt  = w + 1097760;        // 16384 (zeroed by k_xw blocks 0..31)
    float* st  = w + 1114144;        // 32    (zeroed by k_xw)
    float* sw  = w + 1114176;        // 1

    k_xw<<<NB * CPB, 256, 0, stream>>>(x, Wt, xwp, xt, st);
    k_xwred<<<64, 256, 0, stream>>>(xwp, Wt, xw, sw);
    k_kw<<<512, 256, 0, stream>>>(xw, Wk, bk, sw, kwS);
    k_wqs<<<64, 256, 0, stream>>>(kwS, Wq, bq, bt, wqs, cb2);
    k_ta_xt<<<NB * CPB, 256, 0, stream>>>(x, wqs, cb2, xt, st);
    k_out<<<512, 256, 0, stream>>>(xt, st, Wv, bv, out);
}